// Round 3
// baseline (33216.006 us; speedup 1.0000x reference)
//
#include <hip/hip_runtime.h>
#include <math.h>

#define D 128
#define D2 256
#define STK 48
#define SEQ 128
#define BATCH 32
#define RDPT 12
#define NSYN 64
#define NSEM 128
#define VOC 16384
#define EPSF 1e-6f
#define GB_C 0.8f
#define CG_C 2.0f

struct RParams {
  const int* input_ids;
  const int* prev_syn;
  const int* prev_sem;
  const float* emb_mag;
  const float* emb_phase;
  const float* cell_Wr;
  const float* cell_Wi;
  const float* norm_scale;
  const float* norm_shift;
  const float* modrelu_b;
  const float* VOr;
  const float* VOi;
  const float* halt_W;
  const float* halt_b;
  const float* stk_W;
  const float* stk_b;
  const float* cb_syn;
  const float* cb_sem;
  const float* ctxsyn_W;
  const float* ctxsyn_b;
  const float* ctxsem_W;
  const float* ctxsem_b;
  const float* gate_W;
  const float* gate_b;
  // precomputed
  const float* cbT_syn;   // [256][64]
  const float* cbT_sem;   // [256][128]
  const float* cnrm_syn;  // [64]
  const float* cnrm_sem;  // [128]
  const float* gbsig_syn; // [64][64]  = GB*sigmoid(adj_syn)
  const float* gbsig_sem; // [128][128]
  float* X;
  float* lossp;
};

__device__ __forceinline__ float waveAllSum(float v) {
  #pragma unroll
  for (int m = 32; m; m >>= 1) v += __shfl_xor(v, m);
  return v;
}

// ---- VQ distance/energy partial dots: all 8 waves, wave w handles k-chunk
template <int NCB>
__device__ __forceinline__ void vq_dots(const float* __restrict__ cbT,
                                        const float* __restrict__ cW,
                                        const float* zsrc, float* vqd_p,
                                        float* vqe_p, int w, int l) {
  const int kbase = w * 32;
  if (NCB == 64) {
    const int c = l;
    float da = 0.f, ea = 0.f;
    #pragma unroll
    for (int kk = 0; kk < 32; ++kk) {
      const int k = kbase + kk;
      float zv = zsrc[k];
      da = fmaf(cbT[k * 64 + c], zv, da);
      ea = fmaf(cW[k * 64 + c], zv, ea);
    }
    vqd_p[w * 64 + c] = da;
    vqe_p[w * 64 + c] = ea;
  } else {
    const int c0 = l, c1 = l + 64;
    float d0 = 0.f, e0 = 0.f, d1 = 0.f, e1 = 0.f;
    #pragma unroll
    for (int kk = 0; kk < 32; ++kk) {
      const int k = kbase + kk;
      float zv = zsrc[k];
      d0 = fmaf(cbT[k * 128 + c0], zv, d0);
      e0 = fmaf(cW[k * 128 + c0], zv, e0);
      d1 = fmaf(cbT[k * 128 + c1], zv, d1);
      e1 = fmaf(cW[k * 128 + c1], zv, e1);
    }
    vqd_p[w * 128 + c0] = d0; vqe_p[w * 128 + c0] = e0;
    vqd_p[w * 128 + c1] = d1; vqe_p[w * 128 + c1] = e1;
  }
}

// ---- VQ selection: wave 0 only, butterfly softmax+argmin, writes icb[slot]
template <int NCB>
__device__ __forceinline__ void vq_select(const float* __restrict__ cnrm,
                                          const float* __restrict__ cbias,
                                          const float* __restrict__ gbsig,
                                          const float* vqd_p,
                                          const float* vqe_p, int* icb,
                                          int slot, int l) {
  const int pidx = icb[slot];
  if (NCB == 64) {
    float d = cnrm[l], e = cbias[l];
    #pragma unroll
    for (int w = 0; w < 8; ++w) {
      d -= 2.f * vqd_p[w * 64 + l];
      e += vqe_p[w * 64 + l];
    }
    float m = e;
    #pragma unroll
    for (int mm = 32; mm; mm >>= 1) m = fmaxf(m, __shfl_xor(m, mm));
    float ex = expf(e - m);
    float s = waveAllSum(ex);
    float score = d - gbsig[pidx * 64 + l] - CG_C * (ex / s);
    float bv = score; int bi = l;
    #pragma unroll
    for (int mm = 32; mm; mm >>= 1) {
      float ov = __shfl_xor(bv, mm); int oi = __shfl_xor(bi, mm);
      if (ov < bv || (ov == bv && oi < bi)) { bv = ov; bi = oi; }
    }
    if (l == 0) icb[slot] = bi;
  } else {
    float d0 = cnrm[l], e0 = cbias[l];
    float d1 = cnrm[l + 64], e1 = cbias[l + 64];
    #pragma unroll
    for (int w = 0; w < 8; ++w) {
      d0 -= 2.f * vqd_p[w * 128 + l];      e0 += vqe_p[w * 128 + l];
      d1 -= 2.f * vqd_p[w * 128 + l + 64]; e1 += vqe_p[w * 128 + l + 64];
    }
    float m = fmaxf(e0, e1);
    #pragma unroll
    for (int mm = 32; mm; mm >>= 1) m = fmaxf(m, __shfl_xor(m, mm));
    float x0 = expf(e0 - m), x1 = expf(e1 - m);
    float s = waveAllSum(x0 + x1);
    float s0 = d0 - gbsig[pidx * 128 + l]      - CG_C * (x0 / s);
    float s1 = d1 - gbsig[pidx * 128 + l + 64] - CG_C * (x1 / s);
    float bv = s0; int bi = l;
    if (s1 < bv) { bv = s1; bi = l + 64; }
    #pragma unroll
    for (int mm = 32; mm; mm >>= 1) {
      float ov = __shfl_xor(bv, mm); int oi = __shfl_xor(bi, mm);
      if (ov < bv || (ov == bv && oi < bi)) { bv = ov; bi = oi; }
    }
    if (l == 0) icb[slot] = bi;
  }
}

// in-wave complex linear: lane (j = w*16+(l&15), kq = l>>4); weights in regs.
// After butterfly all lanes hold the full column sums (ar, ai).
#define CLIN_IW(WR, WI, XR, XI)                                            \
  float ar, ai;                                                            \
  {                                                                        \
    const float4* x4r = (const float4*)((XR) + k0);                        \
    const float4* x4i = (const float4*)((XI) + k0);                        \
    float r0 = 0.f, r1 = 0.f, i0 = 0.f, i1 = 0.f;                          \
    _Pragma("unroll")                                                      \
    for (int q = 0; q < 8; ++q) {                                          \
      float4 xa = x4r[q];                                                  \
      float4 xb = x4i[q];                                                  \
      float& rr = (q & 1) ? r1 : r0;                                       \
      float& ii = (q & 1) ? i1 : i0;                                       \
      rr = fmaf(xa.x, WR[q*4+0], rr); rr = fmaf(-xb.x, WI[q*4+0], rr);     \
      ii = fmaf(xb.x, WR[q*4+0], ii); ii = fmaf(xa.x, WI[q*4+0], ii);      \
      rr = fmaf(xa.y, WR[q*4+1], rr); rr = fmaf(-xb.y, WI[q*4+1], rr);     \
      ii = fmaf(xb.y, WR[q*4+1], ii); ii = fmaf(xa.y, WI[q*4+1], ii);      \
      rr = fmaf(xa.z, WR[q*4+2], rr); rr = fmaf(-xb.z, WI[q*4+2], rr);     \
      ii = fmaf(xb.z, WR[q*4+2], ii); ii = fmaf(xa.z, WI[q*4+2], ii);      \
      rr = fmaf(xa.w, WR[q*4+3], rr); rr = fmaf(-xb.w, WI[q*4+3], rr);     \
      ii = fmaf(xb.w, WR[q*4+3], ii); ii = fmaf(xa.w, WI[q*4+3], ii);      \
    }                                                                      \
    ar = r0 + r1; ai = i0 + i1;                                            \
    ar += __shfl_xor(ar, 16); ar += __shfl_xor(ar, 32);                    \
    ai += __shfl_xor(ai, 16); ai += __shfl_xor(ai, 32);                    \
  }

__global__ __launch_bounds__(512, 2) void recur_kernel(RParams p) {
  __shared__ float G1[D2 * D];          // gate_W rows 0..255 (128KB)
  __shared__ float vqd_p[1024], vqe_p[1024];
  __shared__ float part[512];
  __shared__ float rd_[D2], zfc[D2], acc2[D2], sl2[D2], zqs[D2];
  __shared__ float xr_[D], xi_[D], cr_[D], ci_[D], rA[D], iA[D], marr[D];
  __shared__ float sptr[STK], nptrs[STK], wms[STK];
  __shared__ float sns[D], nsh[D], smb[D], sgb[D];
  __shared__ float shW[D2];
  __shared__ float sstW[D2 * 3];
  __shared__ float scal[8];
  __shared__ int icb[2];
  __shared__ int ids[SEQ];

  const int tid = threadIdx.x;
  const int b = blockIdx.x;
  const int w = tid >> 6;
  const int l = tid & 63;
  const int j = (w << 4) | (l & 15);
  const int kq = l >> 4;
  const int k0 = kq * 32;

  // persistent weights in registers
  float cwr[32], cwi[32], owr[32], owi[32];
  #pragma unroll
  for (int kk = 0; kk < 32; ++kk) {
    cwr[kk] = p.cell_Wr[(k0 + kk) * D + j];
    cwi[kk] = p.cell_Wi[(k0 + kk) * D + j];
    owr[kk] = p.VOr[(k0 + kk) * D + j];
    owi[kk] = p.VOi[(k0 + kk) * D + j];
  }
  {
    const float4* g4 = (const float4*)p.gate_W;
    float4* l4 = (float4*)G1;
    for (int e = tid; e < D2 * D / 4; e += 512) l4[e] = g4[e];
  }
  if (tid < D2) shW[tid] = p.halt_W[tid];
  for (int e = tid; e < D2 * 3; e += 512) sstW[e] = p.stk_W[e];
  if (tid < D) {
    sns[tid] = p.norm_scale[tid];
    nsh[tid] = p.norm_shift[tid];
    smb[tid] = p.modrelu_b[tid];
    sgb[tid] = p.gate_b[tid];
  }
  if (tid < SEQ) ids[tid] = p.input_ids[b * SEQ + tid];
  if (tid < STK) sptr[tid] = (tid == 0) ? 1.f : 0.f;
  if (tid == 0) { icb[0] = p.prev_syn[b]; icb[1] = p.prev_sem[b]; }
  const float hb = p.halt_b[0];
  const float sb0 = p.stk_b[0], sb1 = p.stk_b[1], sb2 = p.stk_b[2];

  float memv[24];
  #pragma unroll
  for (int q = 0; q < 24; ++q) memv[q] = 0.f;
  float lossAcc = 0.f;
  __syncthreads();

  for (int t = 0; t < SEQ; ++t) {
    // ---- step init
    const int id = ids[t];
    if (tid < D) {
      float m = p.emb_mag[(size_t)id * D + tid];
      float ph = p.emb_phase[(size_t)id * D + tid];
      float sv, cv;
      sincosf(ph, &sv, &cv);
      xr_[tid] = m * cv;
      xi_[tid] = m * sv;
    }
    if (tid < D2) { acc2[tid] = 0.f; sl2[tid] = 0.f; }
    if (tid == 0) scal[0] = 1.f;  // rem
    __syncthreads();

    for (int n = 0; n < RDPT; ++n) {
      // ---- phase 1: cell clin, in-wave combined
      {
        CLIN_IW(cwr, cwi, xr_, xi_);
        if (kq == 0) {
          rA[j] = ar;
          iA[j] = ai;
          marr[j] = sqrtf(ar * ar + ai * ai) + EPSF;
        }
      }
      __syncthreads();
      // ---- phase 2: mean/var (per-wave butterfly) + norm + modReLU
      if (tid < 128) {
        float m0 = marr[l], m1 = marr[l + 64];
        float mean = waveAllSum(m0 + m1) * (1.f / D);
        float dd0 = m0 - mean, dd1 = m1 - mean;
        float istd = rsqrtf(waveAllSum(dd0 * dd0 + dd1 * dd1) * (1.f / (D - 1)) + EPSF);
        float mj = (tid < 64) ? m0 : m1;  // == marr[tid]
        float nm = (mj - mean) * istd * sns[tid] + nsh[tid];
        float r_ = nm * rA[tid] / mj;
        float i_ = nm * iA[tid] / mj;
        float nn = sqrtf(r_ * r_ + i_ * i_) + EPSF;
        float sc = fmaxf(nn + smb[tid], 0.f) / nn;
        cr_[tid] = r_ * sc;
        ci_[tid] = i_ * sc;
      }
      __syncthreads();
      // ---- phase 3: fused v@o clin, in-wave combined
      {
        CLIN_IW(owr, owi, cr_, ci_);
        if (kq == 0) {
          zfc[j] = ar;
          zfc[j + 128] = ai;
        }
      }
      __syncthreads();
      // ---- phase 4: wave-0 mega: heads + softmax + halt + stack ptr
      if (w == 0) {
        float zv0 = zfc[l], zv1 = zfc[l + 64], zv2 = zfc[l + 128], zv3 = zfc[l + 192];
        float sh = zv0 * shW[l] + zv1 * shW[l + 64] + zv2 * shW[l + 128] + zv3 * shW[l + 192];
        float s0 = zv0 * sstW[l * 3] + zv1 * sstW[(l + 64) * 3] + zv2 * sstW[(l + 128) * 3] + zv3 * sstW[(l + 192) * 3];
        float s1 = zv0 * sstW[l * 3 + 1] + zv1 * sstW[(l + 64) * 3 + 1] + zv2 * sstW[(l + 128) * 3 + 1] + zv3 * sstW[(l + 192) * 3 + 1];
        float s2 = zv0 * sstW[l * 3 + 2] + zv1 * sstW[(l + 64) * 3 + 2] + zv2 * sstW[(l + 128) * 3 + 2] + zv3 * sstW[(l + 192) * 3 + 2];
        sh = waveAllSum(sh);
        s0 = waveAllSum(s0);
        s1 = waveAllSum(s1);
        s2 = waveAllSum(s2);
        float halt = 1.f / (1.f + expf(-(sh + hb)));
        float e0 = s0 + sb0, e1 = s1 + sb1, e2 = s2 + sb2;
        float mx = fmaxf(e0, fmaxf(e1, e2));
        float x0 = expf(e0 - mx), x1 = expf(e1 - mx), x2 = expf(e2 - mx);
        float sm = x0 + x1 + x2;
        float push = x0 / sm, pop = x1 / sm, noop = x2 / sm;
        float rem = scal[0];
        if (l == 0) {
          scal[3] = (n == RDPT - 1) ? rem : rem * halt;
          scal[0] = rem * (1.f - halt);
        }
        float pj = 0.f, pu = 0.f, pd = 0.f;
        if (l < STK) {
          pj = sptr[l];
          pu = sptr[(l + STK - 1) % STK];
          pd = sptr[(l + 1) % STK];
        }
        float np_ = push * pu + pop * pd + noop * pj;
        float wm_ = push * pu;
        float ssum = waveAllSum((l < STK) ? np_ : 0.f);
        float inv = 1.f / (ssum + EPSF);
        if (l < STK) {
          np_ *= inv;
          nptrs[l] = np_;
          sptr[l] = np_;
          wms[l] = wm_;
        }
      }
      __syncthreads();
      // ---- phase 5: stack mem update + read; in-wave combine -> rd_
      {
        const int dl = (w << 5) | (l & 31);
        const int jh = l >> 5;
        float zfd = zfc[dl];
        float acc = 0.f;
        #pragma unroll
        for (int jj = 0; jj < 24; ++jj) {
          const int jr = jh * 24 + jj;
          float wmj = wms[jr];
          memv[jj] = wmj * zfd + memv[jj] * (1.f - wmj);
          acc = fmaf(memv[jj], nptrs[jr], acc);
        }
        acc += __shfl_xor(acc, 32);
        if (jh == 0) rd_[dl] = acc;
      }
      __syncthreads();
      // ---- phase 6: gate partials (q2 mapping: waves 0-3 LDS, 4-7 L2)
      {
        const int j2 = tid & 127, q2 = tid >> 7;
        float gacc = 0.f;
        if (q2 < 2) {
          const int kb = q2 * 128;
          #pragma unroll 16
          for (int kk = 0; kk < 128; ++kk)
            gacc = fmaf(zfc[kb + kk], G1[(kb + kk) * D + j2], gacc);
        } else {
          const int kb = (q2 - 2) * 128;
          const float* gp = p.gate_W + (size_t)(D2 + kb) * D + j2;
          #pragma unroll 16
          for (int kk = 0; kk < 128; ++kk)
            gacc = fmaf(rd_[kb + kk], gp[(size_t)kk * D], gacc);
        }
        part[tid] = gacc;
      }
      __syncthreads();
      // ---- phase 7: sigmoid gate + gated residual + accumulators
      if (tid < D) {
        float g = part[tid] + part[tid + 128] + part[tid + 256] + part[tid + 384] + sgb[tid];
        g = 1.f / (1.f + expf(-g));
        float pr_ = zfc[tid], pi_ = zfc[tid + 128];
        float rr_ = rd_[tid], ri_ = rd_[tid + 128];
        float nzr = (1.f - g) * pr_ + g * pi_ + g * (rr_ - ri_);
        float nzi = (1.f - g) * pi_ - g * pr_ + g * (ri_ + rr_);
        xr_[tid] = nzr;
        xi_[tid] = nzi;
        float wgt = scal[3];
        acc2[tid] += wgt * nzr;
        acc2[tid + 128] += wgt * nzi;
        sl2[tid] += nzr * (1.f / RDPT);
        sl2[tid + 128] += nzi * (1.f / RDPT);
      }
      __syncthreads();
    }  // n

    // ---- VQ syn
    vq_dots<NSYN>(p.cbT_syn, p.ctxsyn_W, acc2, vqd_p, vqe_p, w, l);
    __syncthreads();
    if (w == 0)
      vq_select<NSYN>(p.cnrm_syn, p.ctxsyn_b, p.gbsig_syn, vqd_p, vqe_p, icb, 0, l);
    __syncthreads();
    // ---- zq_syn (waves 0-3) + VQ sem dots (all waves)
    if (tid < D2) {
      const int idx = icb[0];
      float zqv = p.cb_syn[idx * D2 + tid];
      float df = zqv - acc2[tid];
      lossAcc += df * df;
      zqs[tid] = zqv;
    }
    vq_dots<NSEM>(p.cbT_sem, p.ctxsem_W, sl2, vqd_p, vqe_p, w, l);
    __syncthreads();
    if (w == 0)
      vq_select<NSEM>(p.cnrm_sem, p.ctxsem_b, p.gbsig_sem, vqd_p, vqe_p, icb, 1, l);
    __syncthreads();
    if (tid < D2) {
      const int idx = icb[1];
      float zqv = p.cb_sem[idx * D2 + tid];
      float df = zqv - sl2[tid];
      lossAcc += df * df;
      p.X[(size_t)(b * SEQ + t) * D2 + tid] = 0.5f * (zqs[tid] + zqv);
    }
    __syncthreads();
  }  // t

  // ---- block loss reduction
  part[tid] = lossAcc;
  __syncthreads();
  if (tid < 256) part[tid] += part[tid + 256];
  __syncthreads();
  if (tid < 128) part[tid] += part[tid + 128];
  __syncthreads();
  if (tid < 64) {
    float v = part[tid] + part[tid + 64];
    #pragma unroll
    for (int off = 32; off; off >>= 1) v += __shfl_down(v, off);
    if (tid == 0) p.lossp[b] = v;
  }
}

// VO = V (complex) @ O (complex)
__global__ __launch_bounds__(256) void voprod_kernel(const float* __restrict__ vr,
                                                     const float* __restrict__ vi,
                                                     const float* __restrict__ orr,
                                                     const float* __restrict__ oii,
                                                     float* __restrict__ VOr,
                                                     float* __restrict__ VOi) {
  __shared__ float a_r[D], a_i[D];
  const int k = blockIdx.x;
  const int tid = threadIdx.x;
  if (tid < D) { a_r[tid] = vr[k * D + tid]; a_i[tid] = vi[k * D + tid]; }
  __syncthreads();
  const int m = tid & 127;
  const int half = tid >> 7;
  float acc = 0.f;
  if (half == 0) {
    #pragma unroll 8
    for (int jj = 0; jj < D; ++jj)
      acc += a_r[jj] * orr[jj * D + m] - a_i[jj] * oii[jj * D + m];
    VOr[k * D + m] = acc;
  } else {
    #pragma unroll 8
    for (int jj = 0; jj < D; ++jj)
      acc += a_r[jj] * oii[jj * D + m] + a_i[jj] * orr[jj * D + m];
    VOi[k * D + m] = acc;
  }
}

// VQ tables: transposed codebooks, row norms, GB*sigmoid(adj)
__global__ void vqprep_kernel(const float* __restrict__ cb_syn,
                              const float* __restrict__ cb_sem,
                              const float* __restrict__ adj_syn,
                              const float* __restrict__ adj_sem,
                              float* __restrict__ cbT_syn,
                              float* __restrict__ cbT_sem,
                              float* __restrict__ cnrm_syn,
                              float* __restrict__ cnrm_sem,
                              float* __restrict__ gbsig_syn,
                              float* __restrict__ gbsig_sem) {
  const int tid = blockIdx.x * 256 + threadIdx.x;
  const int nt = gridDim.x * 256;
  for (int e = tid; e < NSYN * D2; e += nt) {
    int c = e / D2, k = e % D2;
    cbT_syn[k * NSYN + c] = cb_syn[e];
  }
  for (int e = tid; e < NSEM * D2; e += nt) {
    int c = e / D2, k = e % D2;
    cbT_sem[k * NSEM + c] = cb_sem[e];
  }
  for (int c = tid; c < NSYN; c += nt) {
    float s = 0.f;
    for (int k = 0; k < D2; ++k) { float v = cb_syn[c * D2 + k]; s += v * v; }
    cnrm_syn[c] = s;
  }
  for (int c = tid; c < NSEM; c += nt) {
    float s = 0.f;
    for (int k = 0; k < D2; ++k) { float v = cb_sem[c * D2 + k]; s += v * v; }
    cnrm_sem[c] = s;
  }
  for (int e = tid; e < NSYN * NSYN; e += nt)
    gbsig_syn[e] = GB_C / (1.f + expf(-adj_syn[e]));
  for (int e = tid; e < NSEM * NSEM; e += nt)
    gbsig_sem[e] = GB_C / (1.f + expf(-adj_sem[e]));
}

// logits = X @ dec_W + dec_b
__global__ __launch_bounds__(256) void dec_kernel(const float* __restrict__ X,
                                                  const float* __restrict__ W,
                                                  const float* __restrict__ bias,
                                                  float* __restrict__ out) {
  __shared__ float A[32][D2];
  const int tid = threadIdx.x;
  const int bx = blockIdx.x;
  const int by = blockIdx.y;
  const float* xr = X + (size_t)by * 32 * D2;
  #pragma unroll
  for (int s = 0; s < 32; ++s) A[s][tid] = xr[s * D2 + tid];
  __syncthreads();
  const int ty = tid >> 5, tx = tid & 31;
  const int col0 = bx * 128 + tx * 4;
  const int r0 = ty * 4;
  float acc[4][4];
  #pragma unroll
  for (int r = 0; r < 4; ++r) {
    acc[r][0] = 0.f; acc[r][1] = 0.f; acc[r][2] = 0.f; acc[r][3] = 0.f;
  }
  const float* wp = W + col0;
  for (int k = 0; k < D2; k += 4) {
    float4 w0 = *(const float4*)(wp + (size_t)(k + 0) * VOC);
    float4 w1 = *(const float4*)(wp + (size_t)(k + 1) * VOC);
    float4 w2 = *(const float4*)(wp + (size_t)(k + 2) * VOC);
    float4 w3 = *(const float4*)(wp + (size_t)(k + 3) * VOC);
    #pragma unroll
    for (int r = 0; r < 4; ++r) {
      float4 a = *(const float4*)&A[r0 + r][k];
      acc[r][0] += a.x * w0.x + a.y * w1.x + a.z * w2.x + a.w * w3.x;
      acc[r][1] += a.x * w0.y + a.y * w1.y + a.z * w2.y + a.w * w3.y;
      acc[r][2] += a.x * w0.z + a.y * w1.z + a.z * w2.z + a.w * w3.z;
      acc[r][3] += a.x * w0.w + a.y * w1.w + a.z * w2.w + a.w * w3.w;
    }
  }
  float4 bv = *(const float4*)(bias + col0);
  #pragma unroll
  for (int r = 0; r < 4; ++r) {
    float4 o;
    o.x = acc[r][0] + bv.x; o.y = acc[r][1] + bv.y;
    o.z = acc[r][2] + bv.z; o.w = acc[r][3] + bv.w;
    *(float4*)(out + (size_t)(by * 32 + r0 + r) * VOC + col0) = o;
  }
}

__global__ void loss_kernel(const float* __restrict__ lp, float* __restrict__ out) {
  int l = threadIdx.x;
  float v = (l < BATCH) ? lp[l] : 0.f;
  #pragma unroll
  for (int off = 32; off; off >>= 1) v += __shfl_down(v, off);
  if (l == 0) out[0] = v * (1.25f / 8192.f);
}

extern "C" void kernel_launch(void* const* d_in, const int* in_sizes, int n_in,
                              void* d_out, int out_size, void* d_ws,
                              size_t ws_size, hipStream_t stream) {
  float* ws = (float*)d_ws;
  float* X = ws;                      // 1048576
  float* lossp = X + 1048576;         // 64
  float* VOr = lossp + 64;            // 16384
  float* VOi = VOr + 16384;           // 16384
  float* cbT_syn = VOi + 16384;       // 16384
  float* cbT_sem = cbT_syn + 16384;   // 32768
  float* cnrm_syn = cbT_sem + 32768;  // 64
  float* cnrm_sem = cnrm_syn + 64;    // 128
  float* gbsig_syn = cnrm_sem + 128;  // 4096
  float* gbsig_sem = gbsig_syn + 4096;// 16384

  RParams p;
  p.input_ids  = (const int*)d_in[0];
  p.prev_syn   = (const int*)d_in[1];
  p.prev_sem   = (const int*)d_in[2];
  p.emb_mag    = (const float*)d_in[3];
  p.emb_phase  = (const float*)d_in[4];
  p.cell_Wr    = (const float*)d_in[5];
  p.cell_Wi    = (const float*)d_in[6];
  p.norm_scale = (const float*)d_in[7];
  p.norm_shift = (const float*)d_in[8];
  p.modrelu_b  = (const float*)d_in[9];
  p.VOr        = VOr;
  p.VOi        = VOi;
  p.halt_W     = (const float*)d_in[18];
  p.halt_b     = (const float*)d_in[19];
  p.stk_W      = (const float*)d_in[20];
  p.stk_b      = (const float*)d_in[21];
  p.cb_syn     = (const float*)d_in[22];
  p.cb_sem     = (const float*)d_in[23];
  p.ctxsyn_W   = (const float*)d_in[24];
  p.ctxsyn_b   = (const float*)d_in[25];
  p.ctxsem_W   = (const float*)d_in[26];
  p.ctxsem_b   = (const float*)d_in[27];
  p.gate_W     = (const float*)d_in[30];
  p.gate_b     = (const float*)d_in[31];
  const float* dec_W = (const float*)d_in[32];
  const float* dec_b = (const float*)d_in[33];
  p.cbT_syn = cbT_syn;
  p.cbT_sem = cbT_sem;
  p.cnrm_syn = cnrm_syn;
  p.cnrm_sem = cnrm_sem;
  p.gbsig_syn = gbsig_syn;
  p.gbsig_sem = gbsig_sem;
  p.X = X;
  p.lossp = lossp;

  float* out = (float*)d_out;

  voprod_kernel<<<D, 256, 0, stream>>>((const float*)d_in[14], (const float*)d_in[15],
                                       (const float*)d_in[16], (const float*)d_in[17],
                                       VOr, VOi);
  vqprep_kernel<<<64, 256, 0, stream>>>((const float*)d_in[22], (const float*)d_in[23],
                                        (const float*)d_in[28], (const float*)d_in[29],
                                        cbT_syn, cbT_sem, cnrm_syn, cnrm_sem,
                                        gbsig_syn, gbsig_sem);
  recur_kernel<<<BATCH, 512, 0, stream>>>(p);
  dec_kernel<<<dim3(VOC / 128, BATCH * SEQ / 32), 256, 0, stream>>>(X, dec_W,
                                                                    dec_b, out);
  loss_kernel<<<1, 64, 0, stream>>>(lossp, out + (size_t)BATCH * SEQ * VOC);
}